// Round 1
// baseline (6026.460 us; speedup 1.0000x reference)
//
#include <hip/hip_runtime.h>
#include <math.h>

// Problem constants (match reference)
#define Hn   2560      // hidden units
#define Bn   64        // batch
#define INW  128       // input width
#define ETOT 2048      // total excitatory units (4 areas x 512)
#define HGn  160       // h-groups of 16
#define MAXC 13        // max 128-k chunks per h-group
#define NBLK 160       // grid size == HGn (co-resident: 160 <= 256 CUs @ 1 blk/CU)
#define MAXI 7         // max k-steps per wave: ceil(52/8)

typedef __attribute__((ext_vector_type(8))) _Float16 half8;  // 8 f16 = 4 VGPRs
typedef __attribute__((ext_vector_type(4))) float  floatx4;  // MFMA acc

// ---------------------------------------------------------------------------
// Prep: masked signed W -> MFMA A-fragments, split hi/lo f16 (W to 2^-22 rel).
// Af[(hg*13+c)] = 4 kq x {hi,lo} x 64 lanes x 8 f16 (8 KB per 128-k chunk).
// A[m][k]: m = lane&15, k = (lane>>4)*8 + j.   (unchanged from R9)
// ---------------------------------------------------------------------------
__global__ void build_apack(const float* __restrict__ Wrec,
                            const float* __restrict__ Win,
                            _Float16* __restrict__ Af) {
  int hg = blockIdx.x, c = blockIdx.y;
  int a = (hg < 128) ? (hg >> 5) : ((hg - 128) >> 3);
  int nE = (a == 0 || a == 3) ? 8 : 12;
  int nch = nE + 1 + (a == 0 ? 1 : 0);
  if (c >= nch) return;
  int h0 = hg * 16;
  int tid = threadIdx.x;
  int kq = tid >> 6, L = tid & 63;
  int m = L & 15, q = L >> 4;
  int h = h0 + m;

  const float* src; int k0, stride; float sgn; bool isIn = false;
  if (c < nE)       { k0 = ((a == 0 ? 0 : a - 1) << 9) + (c << 7); src = Wrec; stride = Hn;  sgn =  1.f; }
  else if (c == nE) { k0 = ETOT + (a << 7);                        src = Wrec; stride = Hn;  sgn = -1.f; }
  else              { k0 = 0;                                      src = Win;  stride = INW; sgn =  1.f; isIn = true; }

  _Float16 hi8[8], lo8[8];
  #pragma unroll
  for (int j = 0; j < 8; ++j) {
    int k = k0 + kq * 32 + q * 8 + j;
    float w = fabsf(src[(size_t)h * stride + k]);
    if (!isIn && k == h) w = 0.f;     // remove_diag
    w *= sgn;
    _Float16 wh = (_Float16)w;
    hi8[j] = wh;
    lo8[j] = (_Float16)(w - (float)wh);
  }
  _Float16* outp = Af + (size_t)(hg * MAXC + c) * 4096;
  *(uint4*)(outp + (kq * 2 + 0) * 512 + L * 8) = *(const uint4*)hi8;
  *(uint4*)(outp + (kq * 2 + 1) * 512 + L * 8) = *(const uint4*)lo8;
}

// ---------------------------------------------------------------------------
// Persistent kernel: the R9 per-step body, looped over all T steps in ONE
// dispatch. Changes vs R9:
//  - A-fragments preloaded ONCE into VGPRs (<=7 iters x 32 B = 56 VGPR/thr);
//    the 14.4 MB/step A re-read from LLC is gone.
//  - x state in registers (2 floats/thread); xT global buffer deleted.
//  - per-step global sync = sense-barrier: monotonic agent-scope counter +
//    generation flag (separate cache lines). __threadfence() on arrive
//    (release: L2 writeback so rf reaches LLC) and depart (acquire: L2 inv
//    so stale rf lines refetch). Double-buffered rf => 1 barrier/step.
//  - co-residency: 160 blocks, __launch_bounds__(512,2) caps VGPR<=256 so
//    every block fits on any CU; capacity 256 >= 160 => no deadlock.
// ---------------------------------------------------------------------------
__global__ __launch_bounds__(512, 2) void rnn_persist(
    const _Float16* __restrict__ Af,
    const float* __restrict__ inputs,
    _Float16* __restrict__ rfA, _Float16* __restrict__ rfB,
    const float* __restrict__ brec,
    float* __restrict__ rates,
    unsigned* bcnt, unsigned* bgen, int T)
{
  __shared__ float red[8][1056];     // 8 wave-partials, 16 x 66-padded
  __shared__ float rrt[16][68];      // rates staging (padded)
  __shared__ float bb[16];

  const int hg  = blockIdx.x;
  const int tid = threadIdx.x;
  const int w   = tid >> 6, L = tid & 63;
  const int h0  = hg * 16;
  const int a   = (hg < 128) ? (hg >> 5) : ((hg - 128) >> 3);
  const int nE  = (a == 0 || a == 3) ? 8 : 12;
  const int SK  = (nE + 1 + (a == 0 ? 1 : 0)) * 4;   // 40 / 52 / 52 / 36
  const int ktE0 = (a == 0 ? 0 : a - 1) * 16;
  const int ktI0 = 64 + a * 4;

  if (tid < 16) bb[tid] = brec[h0 + tid];

  // ---- one-time A preload into registers + per-iter metadata ----
  half8 ah[MAXI], al[MAXI];
  int   boff[MAXI];
  bool  act[MAXI], isin[MAXI];
  const _Float16* Abase = Af + (size_t)hg * MAXC * 4096;
  #pragma unroll
  for (int i = 0; i < MAXI; ++i) {
    int ks = w + i * 8;
    act[i]  = ks < SK;
    isin[i] = false;
    boff[i] = 0;
    if (act[i]) {
      int c = ks >> 2, kq = ks & 3;
      const _Float16* Ap = Abase + (size_t)c * 4096 + (size_t)(kq * 2) * 512 + (size_t)L * 8;
      ah[i] = *(const half8*)Ap;
      al[i] = *(const half8*)(Ap + 512);
      if (c <= nE) {           // recurrent chunk: rf offset (half units)
        int kt = (c < nE) ? (ktE0 + c * 4 + kq) : (ktI0 + kq);
        boff[i] = kt * 2048 + L * 8;
      } else {                 // input chunk (area 0): inputs offset base
        isin[i] = true;
        boff[i] = kq * 32 + (L >> 4) * 8;
      }
    }
  }

  float xv[2] = {0.f, 0.f};    // x state: 2 elems/thread, lives in regs

  __syncthreads();             // bb ready

  for (int t = 0; t < T; ++t) {
    const _Float16* __restrict__ rs = (t & 1) ? rfB : rfA;
    _Float16* __restrict__ rd       = (t & 1) ? rfA : rfB;

    floatx4 ac0 = {0.f,0.f,0.f,0.f}, ac1 = {0.f,0.f,0.f,0.f};
    floatx4 ac2 = {0.f,0.f,0.f,0.f}, ac3 = {0.f,0.f,0.f,0.f};

    #pragma unroll
    for (int i = 0; i < MAXI; ++i) {
      if (!act[i]) continue;                       // wave-uniform
      half8 b0, b1, b2, b3;
      if (isin[i]) {                               // input chunk (t-varying)
        const float* ip = inputs + (size_t)t * (Bn * INW) + boff[i];
        int nb = L & 15;
        #pragma unroll
        for (int j = 0; j < 8; ++j) b0[j] = (_Float16)ip[(nb +  0) * INW + j];
        #pragma unroll
        for (int j = 0; j < 8; ++j) b1[j] = (_Float16)ip[(nb + 16) * INW + j];
        #pragma unroll
        for (int j = 0; j < 8; ++j) b2[j] = (_Float16)ip[(nb + 32) * INW + j];
        #pragma unroll
        for (int j = 0; j < 8; ++j) b3[j] = (_Float16)ip[(nb + 48) * INW + j];
      } else {                                     // recurrent chunk from rf
        const _Float16* Bp = rs + boff[i];
        b0 = *(const half8*)(Bp);
        b1 = *(const half8*)(Bp + 512);
        b2 = *(const half8*)(Bp + 1024);
        b3 = *(const half8*)(Bp + 1536);
      }
      ac0 = __builtin_amdgcn_mfma_f32_16x16x32_f16(ah[i], b0, ac0, 0, 0, 0);
      ac0 = __builtin_amdgcn_mfma_f32_16x16x32_f16(al[i], b0, ac0, 0, 0, 0);
      ac1 = __builtin_amdgcn_mfma_f32_16x16x32_f16(ah[i], b1, ac1, 0, 0, 0);
      ac1 = __builtin_amdgcn_mfma_f32_16x16x32_f16(al[i], b1, ac1, 0, 0, 0);
      ac2 = __builtin_amdgcn_mfma_f32_16x16x32_f16(ah[i], b2, ac2, 0, 0, 0);
      ac2 = __builtin_amdgcn_mfma_f32_16x16x32_f16(al[i], b2, ac2, 0, 0, 0);
      ac3 = __builtin_amdgcn_mfma_f32_16x16x32_f16(ah[i], b3, ac3, 0, 0, 0);
      ac3 = __builtin_amdgcn_mfma_f32_16x16x32_f16(al[i], b3, ac3, 0, 0, 0);
    }

    // dump split-k partials to LDS
    #pragma unroll
    for (int p = 0; p < 4; ++p) {
      int m = (L >> 4) * 4 + p;
      float* rw = &red[w][m * 66 + (L & 15)];
      rw[ 0] = ac0[p];
      rw[16] = ac1[p];
      rw[32] = ac2[p];
      rw[48] = ac3[p];
    }
    __syncthreads();

    // reduce 8 partials + bias + leaky-integrate + retanh (2 elems/thread)
    #pragma unroll
    for (int e = 0; e < 2; ++e) {
      int elem = tid + e * 512;
      int m = elem >> 6, n = elem & 63;
      float s = 0.f;
      #pragma unroll
      for (int j = 0; j < 8; ++j) s += red[j][m * 66 + n];
      float x = 0.8f * xv[e] + 0.2f * (s + bb[m]);   // ALPHA_X = 0.2
      xv[e] = x;
      rrt[m][n] = tanhf(fmaxf(x, 0.f));
    }
    __syncthreads();

    // tid<128: emit next-step r B-fragments (f16), kt = hg>>1 half-tile
    if (tid < 128) {
      int bt = tid >> 5, Lq = tid & 31;
      int Lp = (hg & 1) * 32 + Lq;
      _Float16 v8[8];
      #pragma unroll
      for (int j = 0; j < 8; ++j)
        v8[j] = (_Float16)rrt[(Lq >> 4) * 8 + j][bt * 16 + (Lq & 15)];
      *(uint4*)(rd + (size_t)((hg >> 1) * 4 + bt) * 512 + (size_t)Lp * 8) = *(const uint4*)v8;
    }
    // tid in [256,512): rates[t][b][h0..h0+15] as packed float4 segments
    if (tid >= 256) {
      int tt = tid - 256;
      int b = tt >> 2, hq = tt & 3;
      float4 o = make_float4(rrt[hq * 4 + 0][b], rrt[hq * 4 + 1][b],
                             rrt[hq * 4 + 2][b], rrt[hq * 4 + 3][b]);
      *(float4*)(rates + (size_t)t * (Bn * Hn) + (size_t)b * Hn + h0 + hq * 4) = o;
    }
    __syncthreads();   // drains all block stores (vmcnt 0) before arrive

    // ---- device-wide sense barrier (monotonic count + generation flag) ----
    if (tid == 0) {
      __threadfence();                               // release: L2 wb -> LLC
      unsigned arr = atomicAdd(bcnt, 1u);            // device scope by default
      unsigned tgt = (unsigned)NBLK * (unsigned)(t + 1);
      if (arr == tgt - 1u) {
        __hip_atomic_store(bgen, (unsigned)(t + 1),
                           __ATOMIC_RELEASE, __HIP_MEMORY_SCOPE_AGENT);
      } else {
        while (__hip_atomic_load(bgen, __ATOMIC_RELAXED,
                                 __HIP_MEMORY_SCOPE_AGENT) < (unsigned)(t + 1)) {
          __builtin_amdgcn_s_sleep(2);
        }
      }
      __threadfence();                               // acquire: L2 inv
    }
    __syncthreads();   // block waits for thread0 before next step's rf reads
  }
}

// ---------------------------------------------------------------------------
extern "C" void kernel_launch(void* const* d_in, const int* in_sizes, int n_in,
                              void* d_out, int out_size, void* d_ws, size_t ws_size,
                              hipStream_t stream) {
  const float* inputs = (const float*)d_in[0];   // [T, 64, 128]
  const float* Wrec   = (const float*)d_in[1];   // [2560, 2560]
  const float* brec   = (const float*)d_in[2];   // [2560]
  const float* Win    = (const float*)d_in[3];   // [2560, 128]
  int T = in_sizes[0] / (Bn * INW);              // 500

  char* base = (char*)d_ws;
  size_t off = 0;
  _Float16* Af  = (_Float16*)(base + off); off += (size_t)HGn * MAXC * 4096 * 2;  // 17.0 MB
  _Float16* rfA = (_Float16*)(base + off); off += (size_t)80 * 4 * 512 * 2;       // 320 KB
  _Float16* rfB = (_Float16*)(base + off); off += (size_t)80 * 4 * 512 * 2;       // 320 KB
  unsigned* bar = (unsigned*)(base + off); off += 512;                            // barrier state

  // x0 = 0 (in-reg); r0 = retanh(0) = 0 (f16 zero == 0x0000); ws poisoned
  // each call so rfA and the barrier counters must be re-zeroed every launch.
  hipMemsetAsync(rfA, 0, (size_t)80 * 4 * 512 * 2, stream);
  hipMemsetAsync(bar, 0, 512, stream);

  build_apack<<<dim3(HGn, MAXC), 256, 0, stream>>>(Wrec, Win, Af);

  float* rates = (float*)d_out;
  rnn_persist<<<NBLK, 512, 0, stream>>>(Af, inputs, rfA, rfB, brec, rates,
                                        bar, bar + 64, T);
}

// Round 4
// 2855.823 us; speedup vs baseline: 2.1102x; 2.1102x over previous
//
#include <hip/hip_runtime.h>
#include <math.h>

// Problem constants (match reference)
#define Hn   2560      // hidden units
#define Bn   64        // batch
#define INW  128       // input width
#define ETOT 2048      // total excitatory units (4 areas x 512)
#define HGn  160       // h-groups of 16
#define MAXC 13        // max 128-k chunks per h-group
#define NBLK 160       // grid size == HGn (co-resident: 160 <= 256 CUs @ 1 blk/CU)
#define MAXI 7         // max k-steps per wave: ceil(52/8)

typedef __attribute__((ext_vector_type(8))) _Float16 half8;  // 8 f16 = 4 VGPRs
typedef __attribute__((ext_vector_type(4))) float  floatx4;  // MFMA acc / NT store

// ---------------------------------------------------------------------------
// Prep: masked signed W -> MFMA A-fragments, split hi/lo f16 (W to 2^-22 rel).
// Af[(hg*13+c)] = 4 kq x {hi,lo} x 64 lanes x 8 f16 (8 KB per 128-k chunk).
// A[m][k]: m = lane&15, k = (lane>>4)*8 + j.   (unchanged)
// ---------------------------------------------------------------------------
__global__ void build_apack(const float* __restrict__ Wrec,
                            const float* __restrict__ Win,
                            _Float16* __restrict__ Af) {
  int hg = blockIdx.x, c = blockIdx.y;
  int a = (hg < 128) ? (hg >> 5) : ((hg - 128) >> 3);
  int nE = (a == 0 || a == 3) ? 8 : 12;
  int nch = nE + 1 + (a == 0 ? 1 : 0);
  if (c >= nch) return;
  int h0 = hg * 16;
  int tid = threadIdx.x;
  int kq = tid >> 6, L = tid & 63;
  int m = L & 15, q = L >> 4;
  int h = h0 + m;

  const float* src; int k0, stride; float sgn; bool isIn = false;
  if (c < nE)       { k0 = ((a == 0 ? 0 : a - 1) << 9) + (c << 7); src = Wrec; stride = Hn;  sgn =  1.f; }
  else if (c == nE) { k0 = ETOT + (a << 7);                        src = Wrec; stride = Hn;  sgn = -1.f; }
  else              { k0 = 0;                                      src = Win;  stride = INW; sgn =  1.f; isIn = true; }

  _Float16 hi8[8], lo8[8];
  #pragma unroll
  for (int j = 0; j < 8; ++j) {
    int k = k0 + kq * 32 + q * 8 + j;
    float w = fabsf(src[(size_t)h * stride + k]);
    if (!isIn && k == h) w = 0.f;     // remove_diag
    w *= sgn;
    _Float16 wh = (_Float16)w;
    hi8[j] = wh;
    lo8[j] = (_Float16)(w - (float)wh);
  }
  _Float16* outp = Af + (size_t)(hg * MAXC + c) * 4096;
  *(uint4*)(outp + (kq * 2 + 0) * 512 + L * 8) = *(const uint4*)hi8;
  *(uint4*)(outp + (kq * 2 + 1) * 512 + L * 8) = *(const uint4*)lo8;
}

// ---- LLC-coherent (sc0 sc1: performed at MALL, bypass L1/L2) rf access ----
// waitcnt lives INSIDE the asm block with its loads => no hoisting hazard.
#define LOAD4(B0,B1,B2,B3,P) \
  asm volatile("global_load_dwordx4 %0, %4, off sc0 sc1\n\t" \
               "global_load_dwordx4 %1, %4, off offset:1024 sc0 sc1\n\t" \
               "global_load_dwordx4 %2, %4, off offset:2048 sc0 sc1\n\t" \
               "global_load_dwordx4 %3, %4, off offset:3072 sc0 sc1\n\t" \
               "s_waitcnt vmcnt(0)" \
               : "=&v"(B0), "=&v"(B1), "=&v"(B2), "=&v"(B3) \
               : "v"(P) : "memory")

#define LOAD8(X0,X1,X2,X3,Y0,Y1,Y2,Y3,PA,PB) \
  asm volatile("global_load_dwordx4 %0, %8, off sc0 sc1\n\t" \
               "global_load_dwordx4 %1, %8, off offset:1024 sc0 sc1\n\t" \
               "global_load_dwordx4 %2, %8, off offset:2048 sc0 sc1\n\t" \
               "global_load_dwordx4 %3, %8, off offset:3072 sc0 sc1\n\t" \
               "global_load_dwordx4 %4, %9, off sc0 sc1\n\t" \
               "global_load_dwordx4 %5, %9, off offset:1024 sc0 sc1\n\t" \
               "global_load_dwordx4 %6, %9, off offset:2048 sc0 sc1\n\t" \
               "global_load_dwordx4 %7, %9, off offset:3072 sc0 sc1\n\t" \
               "s_waitcnt vmcnt(0)" \
               : "=&v"(X0), "=&v"(X1), "=&v"(X2), "=&v"(X3), \
                 "=&v"(Y0), "=&v"(Y1), "=&v"(Y2), "=&v"(Y3) \
               : "v"(PA), "v"(PB) : "memory")

#define MFMA8(i, B0,B1,B2,B3) do { \
  ac0 = __builtin_amdgcn_mfma_f32_16x16x32_f16(ah[i], B0, ac0, 0, 0, 0); \
  ac0 = __builtin_amdgcn_mfma_f32_16x16x32_f16(al[i], B0, ac0, 0, 0, 0); \
  ac1 = __builtin_amdgcn_mfma_f32_16x16x32_f16(ah[i], B1, ac1, 0, 0, 0); \
  ac1 = __builtin_amdgcn_mfma_f32_16x16x32_f16(al[i], B1, ac1, 0, 0, 0); \
  ac2 = __builtin_amdgcn_mfma_f32_16x16x32_f16(ah[i], B2, ac2, 0, 0, 0); \
  ac2 = __builtin_amdgcn_mfma_f32_16x16x32_f16(al[i], B2, ac2, 0, 0, 0); \
  ac3 = __builtin_amdgcn_mfma_f32_16x16x32_f16(ah[i], B3, ac3, 0, 0, 0); \
  ac3 = __builtin_amdgcn_mfma_f32_16x16x32_f16(al[i], B3, ac3, 0, 0, 0); \
} while (0)

#define RECPATH1(i) do { \
  half8 B0_, B1_, B2_, B3_; \
  const _Float16* pp_ = rs + boff[i]; \
  LOAD4(B0_, B1_, B2_, B3_, pp_); \
  MFMA8(i, B0_, B1_, B2_, B3_); \
} while (0)

#define INPATH(i) do { \
  const float* ip_ = inputs + (size_t)t * (Bn * INW) + boff[i]; \
  int nb_ = L & 15; \
  half8 B0_, B1_, B2_, B3_; \
  _Pragma("unroll") for (int j = 0; j < 8; ++j) B0_[j] = (_Float16)ip_[(nb_ +  0) * INW + j]; \
  _Pragma("unroll") for (int j = 0; j < 8; ++j) B1_[j] = (_Float16)ip_[(nb_ + 16) * INW + j]; \
  _Pragma("unroll") for (int j = 0; j < 8; ++j) B2_[j] = (_Float16)ip_[(nb_ + 32) * INW + j]; \
  _Pragma("unroll") for (int j = 0; j < 8; ++j) B3_[j] = (_Float16)ip_[(nb_ + 48) * INW + j]; \
  MFMA8(i, B0_, B1_, B2_, B3_); \
} while (0)

// pair of k-steps: when both are recurrent, 8 loads in flight, one waitcnt
#define PAIR(i0, i1) do { \
  bool r0_ = act[i0] && !isin[i0]; \
  bool r1_ = act[i1] && !isin[i1]; \
  if (r0_ && r1_) { \
    half8 X0_,X1_,X2_,X3_,Y0_,Y1_,Y2_,Y3_; \
    const _Float16* pa_ = rs + boff[i0]; \
    const _Float16* pb_ = rs + boff[i1]; \
    LOAD8(X0_,X1_,X2_,X3_,Y0_,Y1_,Y2_,Y3_, pa_, pb_); \
    MFMA8(i0, X0_, X1_, X2_, X3_); \
    MFMA8(i1, Y0_, Y1_, Y2_, Y3_); \
  } else { \
    if (r0_) RECPATH1(i0); else if (act[i0]) INPATH(i0); \
    if (r1_) RECPATH1(i1); else if (act[i1]) INPATH(i1); \
  } \
} while (0)

// ---------------------------------------------------------------------------
// Persistent kernel, fence-free coherence:
//  - rf exchanged via sc0sc1 (MALL-coherent) asm loads/stores. L2 is NEVER
//    written back or invalidated => no threadfence (R1's 160x wbl2+inv/step
//    was the 11.5us/step catastrophe).
//  - A-fragments pinned in VGPRs via opaque asm (R1: VGPR=80 proved the
//    preload was rematerialized; expect ~180 now).
//  - barrier: relaxed agent atomics only (data already at LLC after vmcnt(0)
//    drain). Hierarchical 8x20 sub-counters -> master -> generation flag.
//  - x state in registers; rates via nontemporal stores (don't evict MALL).
// ---------------------------------------------------------------------------
__global__ __launch_bounds__(512, 2) void rnn_persist(
    const _Float16* __restrict__ Af,
    const float* __restrict__ inputs,
    _Float16* __restrict__ rfA, _Float16* __restrict__ rfB,
    const float* __restrict__ brec,
    float* __restrict__ rates,
    unsigned* bar, int T)
{
  __shared__ float red[8][1056];     // 8 wave-partials, 16 x 66-padded
  __shared__ float rrt[16][68];      // rates staging (padded)
  __shared__ float bb[16];

  const int hg  = blockIdx.x;
  const int tid = threadIdx.x;
  const int w   = tid >> 6, L = tid & 63;
  const int h0  = hg * 16;
  const int a   = (hg < 128) ? (hg >> 5) : ((hg - 128) >> 3);
  const int nE  = (a == 0 || a == 3) ? 8 : 12;
  const int SK  = (nE + 1 + (a == 0 ? 1 : 0)) * 4;   // 40 / 52 / 52 / 36
  const int ktE0 = (a == 0 ? 0 : a - 1) * 16;
  const int ktI0 = 64 + a * 4;

  unsigned* bsub = bar + (hg & 7) * 64;   // 8 sub-counters, 256B apart
  unsigned* bmas = bar + 8 * 64;
  unsigned* bgen = bar + 9 * 64;

  if (tid < 16) bb[tid] = brec[h0 + tid];

  // ---- one-time A preload + pin in VGPRs ----
  half8 ah[MAXI], al[MAXI];
  int   boff[MAXI];
  bool  act[MAXI], isin[MAXI];
  const _Float16* Abase = Af + (size_t)hg * MAXC * 4096;
  #pragma unroll
  for (int i = 0; i < MAXI; ++i) {
    half8 zz = {0,0,0,0,0,0,0,0};
    ah[i] = zz; al[i] = zz;
    int ks = w + i * 8;
    act[i]  = ks < SK;
    isin[i] = false;
    boff[i] = 0;
    if (act[i]) {
      int c = ks >> 2, kq = ks & 3;
      const _Float16* Ap = Abase + (size_t)c * 4096 + (size_t)(kq * 2) * 512 + (size_t)L * 8;
      ah[i] = *(const half8*)Ap;
      al[i] = *(const half8*)(Ap + 512);
      if (c <= nE) {           // recurrent chunk: rf offset (half units)
        int kt = (c < nE) ? (ktE0 + c * 4 + kq) : (ktI0 + kq);
        boff[i] = kt * 2048 + L * 8;
      } else {                 // input chunk (area 0): inputs offset base
        isin[i] = true;
        boff[i] = kq * 32 + (L >> 4) * 8;
      }
    }
  }
  // opaque pin: values now "produced" by asm -> cannot be rematerialized
  #pragma unroll
  for (int i = 0; i < MAXI; ++i)
    asm volatile("" : "+v"(ah[i]), "+v"(al[i]));

  float xv[2] = {0.f, 0.f};    // x state: 2 elems/thread, lives in regs

  __syncthreads();             // bb ready

  for (int t = 0; t < T; ++t) {
    const _Float16* __restrict__ rs = (t & 1) ? rfB : rfA;
    _Float16* __restrict__ rd       = (t & 1) ? rfA : rfB;

    floatx4 ac0 = {0.f,0.f,0.f,0.f}, ac1 = {0.f,0.f,0.f,0.f};
    floatx4 ac2 = {0.f,0.f,0.f,0.f}, ac3 = {0.f,0.f,0.f,0.f};

    PAIR(0, 1);
    PAIR(2, 3);
    PAIR(4, 5);
    if (act[6]) { if (!isin[6]) RECPATH1(6); else INPATH(6); }

    // dump split-k partials to LDS
    #pragma unroll
    for (int p = 0; p < 4; ++p) {
      int m = (L >> 4) * 4 + p;
      float* rw = &red[w][m * 66 + (L & 15)];
      rw[ 0] = ac0[p];
      rw[16] = ac1[p];
      rw[32] = ac2[p];
      rw[48] = ac3[p];
    }
    __syncthreads();

    // reduce 8 partials + bias + leaky-integrate + retanh (2 elems/thread)
    #pragma unroll
    for (int e = 0; e < 2; ++e) {
      int elem = tid + e * 512;
      int m = elem >> 6, n = elem & 63;
      float s = 0.f;
      #pragma unroll
      for (int j = 0; j < 8; ++j) s += red[j][m * 66 + n];
      float x = 0.8f * xv[e] + 0.2f * (s + bb[m]);   // ALPHA_X = 0.2
      xv[e] = x;
      rrt[m][n] = tanhf(fmaxf(x, 0.f));
    }
    __syncthreads();

    // tid<128: emit next-step r B-fragments via MALL-coherent stores.
    // Payload built in a half8 SSA value (clang ext_vector) -> direct
    // register asm operand (HIP uint4 struct was an indirect operand: R3).
    // vmcnt(0) inside the asm: the storing wave itself guarantees the data
    // is at the LLC before it reaches the arrival barrier.
    if (tid < 128) {
      int bt = tid >> 5, Lq = tid & 31;
      int Lp = (hg & 1) * 32 + Lq;
      half8 vv;
      #pragma unroll
      for (int j = 0; j < 8; ++j)
        vv[j] = (_Float16)rrt[(Lq >> 4) * 8 + j][bt * 16 + (Lq & 15)];
      _Float16* dst = rd + (size_t)((hg >> 1) * 4 + bt) * 512 + (size_t)Lp * 8;
      asm volatile("global_store_dwordx4 %0, %1, off sc0 sc1\n\t"
                   "s_waitcnt vmcnt(0)"
                   :: "v"(dst), "v"(vv) : "memory");
    }
    // tid in [256,512): rates[t][b][h0..h0+15], nontemporal (don't pollute MALL)
    if (tid >= 256) {
      int tt = tid - 256;
      int b = tt >> 2, hq = tt & 3;
      floatx4 o;
      o.x = rrt[hq * 4 + 0][b];
      o.y = rrt[hq * 4 + 1][b];
      o.z = rrt[hq * 4 + 2][b];
      o.w = rrt[hq * 4 + 3][b];
      __builtin_nontemporal_store(o,
          (floatx4*)(rates + (size_t)t * (Bn * Hn) + (size_t)b * Hn + h0 + hq * 4));
    }
    __syncthreads();   // all waves' rf stores complete (asm-internal vmcnt 0)

    // ---- fence-free device barrier: relaxed agent atomics (LLC-routed) ----
    if (t + 1 < T) {
      if (tid == 0) {
        unsigned g = (unsigned)(t + 1);
        bool done = false;
        unsigned s = __hip_atomic_fetch_add(bsub, 1u, __ATOMIC_RELAXED,
                                            __HIP_MEMORY_SCOPE_AGENT);
        if (s == g * 20u - 1u) {
          unsigned m2 = __hip_atomic_fetch_add(bmas, 1u, __ATOMIC_RELAXED,
                                               __HIP_MEMORY_SCOPE_AGENT);
          if (m2 == g * 8u - 1u) {
            __hip_atomic_store(bgen, g, __ATOMIC_RELAXED,
                               __HIP_MEMORY_SCOPE_AGENT);
            done = true;
          }
        }
        if (!done) {
          while (__hip_atomic_load(bgen, __ATOMIC_RELAXED,
                                   __HIP_MEMORY_SCOPE_AGENT) < g)
            __builtin_amdgcn_s_sleep(2);
        }
      }
      __syncthreads();   // block released; next rf reads are sc0sc1 (fresh)
    }
  }
}

// ---------------------------------------------------------------------------
extern "C" void kernel_launch(void* const* d_in, const int* in_sizes, int n_in,
                              void* d_out, int out_size, void* d_ws, size_t ws_size,
                              hipStream_t stream) {
  const float* inputs = (const float*)d_in[0];   // [T, 64, 128]
  const float* Wrec   = (const float*)d_in[1];   // [2560, 2560]
  const float* brec   = (const float*)d_in[2];   // [2560]
  const float* Win    = (const float*)d_in[3];   // [2560, 128]
  int T = in_sizes[0] / (Bn * INW);              // 500

  char* base = (char*)d_ws;
  size_t off = 0;
  _Float16* Af  = (_Float16*)(base + off); off += (size_t)HGn * MAXC * 4096 * 2;  // 17.0 MB
  _Float16* rfA = (_Float16*)(base + off); off += (size_t)80 * 4 * 512 * 2;       // 320 KB
  _Float16* rfB = (_Float16*)(base + off); off += (size_t)80 * 4 * 512 * 2;       // 320 KB
  unsigned* bar = (unsigned*)(base + off); off += 4096;                           // barrier state

  // r0 = retanh(0) = 0 (f16 zero == 0x0000); ws poisoned each call, so rfA
  // and the barrier counters must be re-zeroed every launch.
  (void)hipMemsetAsync(rfA, 0, (size_t)80 * 4 * 512 * 2, stream);
  (void)hipMemsetAsync(bar, 0, 4096, stream);

  build_apack<<<dim3(HGn, MAXC), 256, 0, stream>>>(Wrec, Win, Af);

  float* rates = (float*)d_out;
  rnn_persist<<<NBLK, 512, 0, stream>>>(Af, inputs, rfA, rfB, brec, rates,
                                        bar, T);
}